// Round 1
// baseline (305.561 us; speedup 1.0000x reference)
//
#include <hip/hip_runtime.h>
#include <hip/hip_bf16.h>

// Problem constants
// B=64, N=256, IN=512, OUT=512, K_SLOTS=8, DK=64
// inputs: node_feats (64*256*512 f32), adj (64*8*256*256 f32), weight (512*512 f32), bias (512 f32)
// out: (64*256*512) f32

typedef __attribute__((ext_vector_type(8))) short short8;   // 8 bf16 (4 VGPRs) - MFMA A/B frag
typedef __attribute__((ext_vector_type(4))) float floatx4;  // MFMA C/D frag

__device__ __forceinline__ unsigned short f2bf(float f) {
    union { float f; unsigned u; } v; v.f = f;
    unsigned r = v.u + 0x7FFFu + ((v.u >> 16) & 1u);  // RNE
    return (unsigned short)(r >> 16);
}

// packed f32x2 -> bf16x2 (RNE); compiles to v_cvt_pk_bf16_f32 on gfx950
__device__ __forceinline__ unsigned pk2bf(float a, float b) {
    union { __hip_bfloat162 h; unsigned u; } cv;
    cv.h = __float22bfloat162_rn(make_float2(a, b));
    return cv.u;
}

// ---------------------------------------------------------------------------
// Pre-kernel: W (512x512, row-major [k][o]) -> Wt bf16 [o][k] (k contiguous)
// ---------------------------------------------------------------------------
__global__ __launch_bounds__(256) void wt_kernel(const float* __restrict__ W,
                                                 unsigned short* __restrict__ Wt) {
    __shared__ unsigned short t_lds[64 * 66];  // [o][k], pad 66 -> 2-way (free)
    const int tile = blockIdx.x;      // 0..63 (8x8 tiles)
    const int k0 = (tile >> 3) * 64;
    const int o0 = (tile & 7) * 64;
    const int t = threadIdx.x;
    const int c = t & 63;             // coalesced dim
    const int rb = t >> 6;            // 0..3
#pragma unroll
    for (int i = 0; i < 16; ++i) {
        int r = i * 4 + rb;           // k-row within tile
        t_lds[c * 66 + r] = f2bf(W[(size_t)(k0 + r) * 512 + o0 + c]);
    }
    __syncthreads();
#pragma unroll
    for (int i = 0; i < 16; ++i) {
        int o_r = i * 4 + rb;         // o-row within tile
        Wt[(size_t)(o0 + o_r) * 512 + k0 + c] = t_lds[o_r * 66 + c];
    }
}

// ---------------------------------------------------------------------------
// Fused kernel: one block per (b, ks). 1024 threads = 16 waves, 2 blocks/CU.
//
// Register-direct MFMA fragments (no LDS staging, no lockstep barriers):
//   A-frag of lane (lrow,quad) for 16x16x32 = 8 CONTIGUOUS elements
//   A[base+lrow][32*kb + 8*quad .. +8]  -> per-lane 32B global load of fp32
//   + 4x v_cvt_pk_bf16_f32 -> short8, straight into the MFMA.
//
//   Stage 1: wave w computes m-rows [16w,16w+16) x all 64 d.
//            A <- X directly (global), B <- Wt directly (bf16, L2-resident).
//            ZERO LDS, ZERO barriers.  Epilogue: bias+relu -> ht (LDS, 32KB).
//   ---- single __syncthreads() ----
//   Stage 2: wave w computes n-rows [16w,16w+16) x all 64 d x full m.
//            A <- adj directly (each 128B line fetched exactly once/block),
//            B <- ht from LDS (16B-block XOR swizzle, only LDS use left).
// ---------------------------------------------------------------------------
__global__ __launch_bounds__(1024, 8) void fused_kernel(
    const float* __restrict__ X, const unsigned short* __restrict__ Wt,
    const float* __restrict__ bias, const float* __restrict__ adj,
    float* __restrict__ out) {
    __shared__ unsigned short ht[64 * 256];  // hT [d][m] bf16, swizzled 16B blocks

    const int id = blockIdx.x;        // 0..511
    const int b = id & 63;            // same-b blocks == mod 8 -> same XCD
    const int ks = id >> 6;

    const int tid = threadIdx.x;
    const int lane = tid & 63, w = tid >> 6;   // wave 0..15
    const int lrow = lane & 15, quad = lane >> 4;

    const float* Xb = X + (size_t)b * 256 * 512;
    const unsigned short* Wslice = Wt + (size_t)ks * 64 * 512;  // [o_local][k]

    // ---------------- Stage 1: X[b] @ W-slice, global->reg fragments ---------
    floatx4 acc1[4];
    const floatx4 fzero = {0.f, 0.f, 0.f, 0.f};
#pragma unroll
    for (int j = 0; j < 4; ++j) acc1[j] = fzero;

    const float* xrow = Xb + (size_t)(w * 16 + lrow) * 512 + quad * 8;
    const unsigned short* wrow = Wslice + (size_t)lrow * 512 + quad * 8;

#pragma unroll 2
    for (int kb = 0; kb < 16; ++kb) {
        const int k0 = kb * 32;
        float4 xa = *(const float4*)(xrow + k0);
        float4 xc = *(const float4*)(xrow + k0 + 4);
        union { short8 s; unsigned u[4]; } af;
        af.u[0] = pk2bf(xa.x, xa.y);
        af.u[1] = pk2bf(xa.z, xa.w);
        af.u[2] = pk2bf(xc.x, xc.y);
        af.u[3] = pk2bf(xc.z, xc.w);
#pragma unroll
        for (int j = 0; j < 4; ++j) {
            short8 bfr = *(const short8*)(wrow + (size_t)j * 16 * 512 + k0);
            acc1[j] = __builtin_amdgcn_mfma_f32_16x16x32_bf16(af.s, bfr, acc1[j], 0, 0, 0);
        }
    }

    // ------------- Stage 1 epilogue: bias+relu+bf16 -> swizzled ht[d][m] -----
#pragma unroll
    for (int j = 0; j < 4; ++j) {
        int d = 16 * j + lrow;               // C/D col = lane&15
        float bv = bias[ks * 64 + d];
        floatx4 c = acc1[j];
        unsigned p01 = pk2bf(fmaxf(c.x + bv, 0.f), fmaxf(c.y + bv, 0.f));
        unsigned p23 = pk2bf(fmaxf(c.z + bv, 0.f), fmaxf(c.w + bv, 0.f));
        int jm = 2 * w + (quad >> 1);        // 16-B block index = m>>3
        int phys = jm ^ (d & 7);             // XOR swizzle
        unsigned* d32 = (unsigned*)(ht + d * 256 + phys * 8 + (quad & 1) * 4);
        d32[0] = p01; d32[1] = p23;          // 8B store (rows m..m+3)
    }
    __syncthreads();   // the ONLY barrier: ht produced -> consumed

    // ------------- Stage 2: adj[b,ks] @ ht -> out, adj direct to registers ---
    const float* Abase = adj + ((size_t)(b * 8 + ks)) * 65536;  // [n][m] 256x256 f32
    const float* arow = Abase + (size_t)(w * 16 + lrow) * 256 + quad * 8;

    floatx4 acc[4];
#pragma unroll
    for (int j = 0; j < 4; ++j) acc[j] = fzero;

#pragma unroll 2
    for (int mt = 0; mt < 8; ++mt) {
        float4 a0 = *(const float4*)(arow + mt * 32);
        float4 a1 = *(const float4*)(arow + mt * 32 + 4);
        union { short8 s; unsigned u[4]; } afr;
        afr.u[0] = pk2bf(a0.x, a0.y);
        afr.u[1] = pk2bf(a0.z, a0.w);
        afr.u[2] = pk2bf(a1.x, a1.y);
        afr.u[3] = pk2bf(a1.z, a1.w);
        const int jm = 4 * mt + quad;        // k-block = (mt*32 + quad*8)/8
#pragma unroll
        for (int dt = 0; dt < 4; ++dt) {
            int d = dt * 16 + lrow;
            short8 bfr = *(const short8*)(ht + d * 256 + ((jm ^ (d & 7)) * 8));
            acc[dt] = __builtin_amdgcn_mfma_f32_16x16x32_bf16(afr.s, bfr, acc[dt], 0, 0, 0);
        }
    }

    // epilogue: C/D col = lane&15 (d), row = quad*4+reg (n)
    const int n_g = w * 16 + quad * 4;
    float* dst = out + ((size_t)b * 256 + n_g) * 512 + ks * 64 + lrow;
#pragma unroll
    for (int dt = 0; dt < 4; ++dt) {
        float* p = dst + dt * 16;
        p[0 * 512] = acc[dt].x;
        p[1 * 512] = acc[dt].y;
        p[2 * 512] = acc[dt].z;
        p[3 * 512] = acc[dt].w;
    }
}

// ---------------------------------------------------------------------------
extern "C" void kernel_launch(void* const* d_in, const int* in_sizes, int n_in,
                              void* d_out, int out_size, void* d_ws, size_t ws_size,
                              hipStream_t stream) {
    const float* X    = (const float*)d_in[0];  // node_feats
    const float* adj  = (const float*)d_in[1];  // adj
    const float* W    = (const float*)d_in[2];  // weight
    const float* bias = (const float*)d_in[3];  // bias
    float* out = (float*)d_out;

    // workspace: Wt bf16 [512*512] only
    unsigned short* Wt = (unsigned short*)d_ws;

    wt_kernel<<<64, 256, 0, stream>>>(W, Wt);
    fused_kernel<<<512, 1024, 0, stream>>>(X, Wt, bias, adj, out);
}

// Round 2
// 271.420 us; speedup vs baseline: 1.1258x; 1.1258x over previous
//
#include <hip/hip_runtime.h>
#include <hip/hip_bf16.h>

// Problem constants
// B=64, N=256, IN=512, OUT=512, K_SLOTS=8, DK=64
// inputs: node_feats (64*256*512 f32), adj (64*8*256*256 f32), weight (512*512 f32), bias (512 f32)
// out: (64*256*512) f32

typedef __attribute__((ext_vector_type(8))) short short8;   // 8 bf16 (4 VGPRs) - MFMA A/B frag
typedef __attribute__((ext_vector_type(4))) float floatx4;  // MFMA C/D frag

__device__ __forceinline__ unsigned short f2bf(float f) {
    union { float f; unsigned u; } v; v.f = f;
    unsigned r = v.u + 0x7FFFu + ((v.u >> 16) & 1u);  // RNE
    return (unsigned short)(r >> 16);
}

// packed f32x2 -> bf16x2 (RNE); compiles to v_cvt_pk_bf16_f32 on gfx950
__device__ __forceinline__ unsigned pk2bf(float a, float b) {
    union { __hip_bfloat162 h; unsigned u; } cv;
    cv.h = __float22bfloat162_rn(make_float2(a, b));
    return cv.u;
}

// ---------------------------------------------------------------------------
// Pre-kernel: W (512x512, row-major [k][o]) -> Wt bf16 [o][k] (k contiguous)
// ---------------------------------------------------------------------------
__global__ __launch_bounds__(256) void wt_kernel(const float* __restrict__ W,
                                                 unsigned short* __restrict__ Wt) {
    __shared__ unsigned short t_lds[64 * 66];  // [o][k], pad 66 -> 2-way (free)
    const int tile = blockIdx.x;      // 0..63 (8x8 tiles)
    const int k0 = (tile >> 3) * 64;
    const int o0 = (tile & 7) * 64;
    const int t = threadIdx.x;
    const int c = t & 63;             // coalesced dim
    const int rb = t >> 6;            // 0..3
#pragma unroll
    for (int i = 0; i < 16; ++i) {
        int r = i * 4 + rb;           // k-row within tile
        t_lds[c * 66 + r] = f2bf(W[(size_t)(k0 + r) * 512 + o0 + c]);
    }
    __syncthreads();
#pragma unroll
    for (int i = 0; i < 16; ++i) {
        int o_r = i * 4 + rb;         // o-row within tile
        Wt[(size_t)(o0 + o_r) * 512 + k0 + c] = t_lds[o_r * 66 + c];
    }
}

// ---------------------------------------------------------------------------
// Fused kernel: one block per (b, ks). 512 threads = 8 waves, 2 blocks/CU,
// __launch_bounds__(512,4) -> 128-VGPR budget so loads can stay in flight.
//
// Register-direct MFMA fragments + explicit 2-deep software pipeline:
//   A-frag of lane (lrow,quad) for 16x16x32 = 8 CONTIGUOUS elements ->
//   per-lane 32B global load + 4x v_cvt_pk_bf16_f32, straight into MFMA.
//   Each wave owns TWO 16-row groups (32 rows) -> 2 independent dep chains,
//   B-fragments (Wt / ht) shared across both groups.
//
//   Stage 1: wave w computes m-rows [32w,32w+32) x all 64 d.
//            A <- X (global, dbuf), B <- Wt (bf16, L1/L2-hot, dbuf). No LDS.
//   ---- adj prologue loads issued, then the ONLY __syncthreads ----
//   Stage 2: wave w computes n-rows [32w,32w+32) x all 64 d x full m.
//            A <- adj (global, dbuf; each 128B line fetched once/block),
//            B <- ht in LDS (16B-block XOR swizzle, conflict-free b128).
// ---------------------------------------------------------------------------
__global__ __launch_bounds__(512, 4) void fused_kernel(
    const float* __restrict__ X, const unsigned short* __restrict__ Wt,
    const float* __restrict__ bias, const float* __restrict__ adj,
    float* __restrict__ out) {
    __shared__ unsigned short ht[64 * 256];  // hT [d][m] bf16, swizzled 16B blocks

    const int id = blockIdx.x;        // 0..511
    const int b = id & 63;            // same-b blocks == mod 8 -> same XCD
    const int ks = id >> 6;

    const int tid = threadIdx.x;
    const int lane = tid & 63, w = tid >> 6;   // wave 0..7
    const int lrow = lane & 15, quad = lane >> 4;
    const int m0 = w * 32;            // wave's 32-row slab (m in stage1, n in stage2)

    const float* Xb = X + (size_t)b * 256 * 512;
    const unsigned short* Wslice = Wt + (size_t)ks * 64 * 512;  // [o_local][k]

    const float* xrow0 = Xb + (size_t)(m0 + lrow) * 512 + quad * 8;
    const float* xrow1 = xrow0 + 16 * 512;
    const unsigned short* wrow = Wslice + (size_t)lrow * 512 + quad * 8;

    // bias for this lane's 4 d-columns (hoisted; tiny, L2-hot)
    float bv[4];
#pragma unroll
    for (int j = 0; j < 4; ++j) bv[j] = bias[ks * 64 + 16 * j + lrow];

    // ---------------- Stage 1: X[b] @ W-slice, 2-deep pipelined ---------------
    floatx4 acc1[2][4];
    const floatx4 fzero = {0.f, 0.f, 0.f, 0.f};
#pragma unroll
    for (int g = 0; g < 2; ++g)
#pragma unroll
        for (int j = 0; j < 4; ++j) acc1[g][j] = fzero;

    float4 xb_[2][2][2];   // [buf][group][half]
    short8 wb_[2][4];      // [buf][j]

#define LOAD_S1(buf, kb) do {                                           \
        const int k0_ = (kb) * 32;                                      \
        xb_[buf][0][0] = *(const float4*)(xrow0 + k0_);                 \
        xb_[buf][0][1] = *(const float4*)(xrow0 + k0_ + 4);             \
        xb_[buf][1][0] = *(const float4*)(xrow1 + k0_);                 \
        xb_[buf][1][1] = *(const float4*)(xrow1 + k0_ + 4);             \
        wb_[buf][0] = *(const short8*)(wrow + k0_);                     \
        wb_[buf][1] = *(const short8*)(wrow + 16 * 512 + k0_);          \
        wb_[buf][2] = *(const short8*)(wrow + 32 * 512 + k0_);          \
        wb_[buf][3] = *(const short8*)(wrow + 48 * 512 + k0_);          \
    } while (0)

    LOAD_S1(0, 0);
#pragma unroll
    for (int kb = 0; kb < 16; ++kb) {
        const int cur = kb & 1;
        if (kb < 15) LOAD_S1(cur ^ 1, kb + 1);   // static after unroll
#pragma unroll
        for (int g = 0; g < 2; ++g) {
            union { short8 s; unsigned u[4]; } af;
            const float4 va = xb_[cur][g][0], vc = xb_[cur][g][1];
            af.u[0] = pk2bf(va.x, va.y);
            af.u[1] = pk2bf(va.z, va.w);
            af.u[2] = pk2bf(vc.x, vc.y);
            af.u[3] = pk2bf(vc.z, vc.w);
#pragma unroll
            for (int j = 0; j < 4; ++j)
                acc1[g][j] = __builtin_amdgcn_mfma_f32_16x16x32_bf16(
                    af.s, wb_[cur][j], acc1[g][j], 0, 0, 0);
        }
    }
#undef LOAD_S1

    // -- issue stage-2 prologue loads early (independent of ht / barrier) -----
    const float* Abase = adj + ((size_t)(b * 8 + ks)) * 65536;  // [n][m] 256x256 f32
    const float* arow0 = Abase + (size_t)(m0 + lrow) * 256 + quad * 8;
    const float* arow1 = arow0 + 16 * 256;

    float4 ab_[2][2][2];   // [buf][group][half]
#define LOAD_S2(buf, mt) do {                                           \
        ab_[buf][0][0] = *(const float4*)(arow0 + (mt) * 32);           \
        ab_[buf][0][1] = *(const float4*)(arow0 + (mt) * 32 + 4);       \
        ab_[buf][1][0] = *(const float4*)(arow1 + (mt) * 32);           \
        ab_[buf][1][1] = *(const float4*)(arow1 + (mt) * 32 + 4);       \
    } while (0)

    LOAD_S2(0, 0);

    // ------------- Stage 1 epilogue: bias+relu+bf16 -> swizzled ht[d][m] -----
#pragma unroll
    for (int g = 0; g < 2; ++g) {
#pragma unroll
        for (int j = 0; j < 4; ++j) {
            int d = 16 * j + lrow;               // C/D col = lane&15
            floatx4 c = acc1[g][j];
            unsigned p01 = pk2bf(fmaxf(c.x + bv[j], 0.f), fmaxf(c.y + bv[j], 0.f));
            unsigned p23 = pk2bf(fmaxf(c.z + bv[j], 0.f), fmaxf(c.w + bv[j], 0.f));
            int jm = 4 * w + 2 * g + (quad >> 1);  // 16-B block index = m>>3
            int phys = jm ^ (d & 7);               // XOR swizzle
            unsigned* d32 = (unsigned*)(ht + d * 256 + phys * 8 + (quad & 1) * 4);
            d32[0] = p01; d32[1] = p23;            // 8B store (rows m..m+3)
        }
    }
    __syncthreads();   // the ONLY barrier: ht produced -> consumed

    // ------------- Stage 2: adj[b,ks] @ ht -> out, 2-deep pipelined ----------
    floatx4 acc2[2][4];
#pragma unroll
    for (int g = 0; g < 2; ++g)
#pragma unroll
        for (int j = 0; j < 4; ++j) acc2[g][j] = fzero;

#pragma unroll
    for (int mt = 0; mt < 8; ++mt) {
        const int cur = mt & 1;
        if (mt < 7) LOAD_S2(cur ^ 1, mt + 1);    // static after unroll
        const int jm = 4 * mt + quad;            // k-block = (mt*32 + quad*8)/8
        short8 hfr[4];
#pragma unroll
        for (int dt = 0; dt < 4; ++dt) {
            int d = dt * 16 + lrow;
            hfr[dt] = *(const short8*)(ht + d * 256 + ((jm ^ (d & 7)) * 8));
        }
#pragma unroll
        for (int g = 0; g < 2; ++g) {
            union { short8 s; unsigned u[4]; } af;
            const float4 va = ab_[cur][g][0], vc = ab_[cur][g][1];
            af.u[0] = pk2bf(va.x, va.y);
            af.u[1] = pk2bf(va.z, va.w);
            af.u[2] = pk2bf(vc.x, vc.y);
            af.u[3] = pk2bf(vc.z, vc.w);
#pragma unroll
            for (int dt = 0; dt < 4; ++dt)
                acc2[g][dt] = __builtin_amdgcn_mfma_f32_16x16x32_bf16(
                    af.s, hfr[dt], acc2[g][dt], 0, 0, 0);
        }
    }
#undef LOAD_S2

    // epilogue: C/D col = lane&15 (d), row = quad*4+reg (n)
#pragma unroll
    for (int g = 0; g < 2; ++g) {
        const int n_g = m0 + g * 16 + quad * 4;
        float* dst = out + ((size_t)b * 256 + n_g) * 512 + ks * 64 + lrow;
#pragma unroll
        for (int dt = 0; dt < 4; ++dt) {
            float* p = dst + dt * 16;
            p[0 * 512] = acc2[g][dt].x;
            p[1 * 512] = acc2[g][dt].y;
            p[2 * 512] = acc2[g][dt].z;
            p[3 * 512] = acc2[g][dt].w;
        }
    }
}

// ---------------------------------------------------------------------------
extern "C" void kernel_launch(void* const* d_in, const int* in_sizes, int n_in,
                              void* d_out, int out_size, void* d_ws, size_t ws_size,
                              hipStream_t stream) {
    const float* X    = (const float*)d_in[0];  // node_feats
    const float* adj  = (const float*)d_in[1];  // adj
    const float* W    = (const float*)d_in[2];  // weight
    const float* bias = (const float*)d_in[3];  // bias
    float* out = (float*)d_out;

    // workspace: Wt bf16 [512*512] only
    unsigned short* Wt = (unsigned short*)d_ws;

    wt_kernel<<<64, 256, 0, stream>>>(W, Wt);
    fused_kernel<<<512, 512, 0, stream>>>(X, Wt, bias, adj, out);
}

// Round 3
// 260.302 us; speedup vs baseline: 1.1739x; 1.0427x over previous
//
#include <hip/hip_runtime.h>
#include <hip/hip_bf16.h>

// Problem constants
// B=64, N=256, IN=512, OUT=512, K_SLOTS=8, DK=64
// inputs: node_feats (64*256*512 f32), adj (64*8*256*256 f32), weight (512*512 f32), bias (512 f32)
// out: (64*256*512) f32

typedef __attribute__((ext_vector_type(8))) short short8;   // 8 bf16 (4 VGPRs) - MFMA A/B frag
typedef __attribute__((ext_vector_type(4))) float floatx4;  // MFMA C/D frag

__device__ __forceinline__ unsigned short f2bf(float f) {
    union { float f; unsigned u; } v; v.f = f;
    unsigned r = v.u + 0x7FFFu + ((v.u >> 16) & 1u);  // RNE
    return (unsigned short)(r >> 16);
}

// packed f32x2 -> bf16x2 (RNE); compiles to v_cvt_pk_bf16_f32 on gfx950
__device__ __forceinline__ unsigned pk2bf(float a, float b) {
    union { __hip_bfloat162 h; unsigned u; } cv;
    cv.h = __float22bfloat162_rn(make_float2(a, b));
    return cv.u;
}

// ---------------------------------------------------------------------------
// Pre-kernel: W (512x512, row-major [k][o]) -> Wt bf16 [o][k] (k contiguous)
// ---------------------------------------------------------------------------
__global__ __launch_bounds__(256) void wt_kernel(const float* __restrict__ W,
                                                 unsigned short* __restrict__ Wt) {
    __shared__ unsigned short t_lds[64 * 66];  // [o][k], pad 66 -> 2-way (free)
    const int tile = blockIdx.x;      // 0..63 (8x8 tiles)
    const int k0 = (tile >> 3) * 64;
    const int o0 = (tile & 7) * 64;
    const int t = threadIdx.x;
    const int c = t & 63;             // coalesced dim
    const int rb = t >> 6;            // 0..3
#pragma unroll
    for (int i = 0; i < 16; ++i) {
        int r = i * 4 + rb;           // k-row within tile
        t_lds[c * 66 + r] = f2bf(W[(size_t)(k0 + r) * 512 + o0 + c]);
    }
    __syncthreads();
#pragma unroll
    for (int i = 0; i < 16; ++i) {
        int o_r = i * 4 + rb;         // o-row within tile
        Wt[(size_t)(o0 + o_r) * 512 + k0 + c] = t_lds[o_r * 66 + c];
    }
}

// ---------------------------------------------------------------------------
// Fused kernel: one block per (b, ks). 512 threads = 8 waves, 64 KB LDS ->
// 2 blocks/CU. id%8 == b%8, so the 8 blocks sharing b land on one XCD and
// X[b] is served from that XCD's L2 (8x reuse never hits HBM).
//
// T14 async-STAGE pipeline (structural overlap; MFMA never depends on
// in-flight global loads, so the compiler cannot serialize it):
//   per step: WRITE(buf^1, regs loaded LAST step)  [vmcnt already drained]
//             LOAD(regs, step+2)                    [in flight over compute]
//             compute(buf)                          [ds_read + MFMA only]
//             __syncthreads()
//
// Staged tiles are bf16 [256 rows][32 cols] (16 KB, x2 dbuf), XOR-swizzled
// phys = j ^ ((row>>1)&3) on 16-B chunks -> 2-way (free) on write and on the
// b128 fragment reads (rows are 64 B, so unswizzled would be 8-way).
//
//   Stage 1 (16 steps of k=32): tiles = X[b] chunk, W register-direct (L2).
//   Stage 2 ( 8 steps of m=32): tiles = adj[b,ks] chunk, B-frags from ht.
// ---------------------------------------------------------------------------
__global__ __launch_bounds__(512, 4) void fused_kernel(
    const float* __restrict__ X, const unsigned short* __restrict__ Wt,
    const float* __restrict__ bias, const float* __restrict__ adj,
    float* __restrict__ out) {
    __shared__ struct {
        unsigned short ht[64 * 256];       // 32 KB: hT [d][m] bf16, swizzled
        unsigned short tile[2][256 * 32];  // 2x16 KB: s1 X-tile / s2 adj-tile
    } lds;

    const int id = blockIdx.x;        // 0..511
    const int b = id & 63;
    const int ks = id >> 6;

    const int tid = threadIdx.x;
    const int lane = tid & 63, w = tid >> 6;   // wave 0..7
    const int lrow = lane & 15, quad = lane >> 4;

    const float* Xb = X + (size_t)b * 256 * 512;
    const unsigned short* Wslice = Wt + (size_t)ks * 64 * 512;  // [o_local][k]
    const float* Abase = adj + ((size_t)(b * 8 + ks)) * 65536;  // [n][m] 256x256

    // ---- staging geometry: thread covers 64 B (16 f32) of one row ----------
    const int srow = tid >> 1;                 // 0..255 (wave w stages rows 32w..)
    const int shalf = tid & 1;                 // which 64-B half of the 128-B step
    const int sswz = (srow >> 1) & 3;
    const int sd0 = srow * 32 + ((((shalf * 2)    ) ^ sswz) * 8);
    const int sd1 = srow * 32 + ((((shalf * 2) + 1) ^ sswz) * 8);
    const float* const xsrc = Xb + (size_t)srow * 512 + shalf * 16;
    const float* const asrc = Abase + (size_t)srow * 256 + shalf * 16;

#define LOADG(r, base, koff) do {                                       \
        const float* s_ = (base) + (koff);                              \
        r[0] = *(const float4*)(s_);                                    \
        r[1] = *(const float4*)(s_ + 4);                                \
        r[2] = *(const float4*)(s_ + 8);                                \
        r[3] = *(const float4*)(s_ + 12);                               \
    } while (0)

#define WRITET(buf, r) do {                                             \
        union { short8 s; unsigned u[4]; } t0_, t1_;                    \
        t0_.u[0] = pk2bf(r[0].x, r[0].y); t0_.u[1] = pk2bf(r[0].z, r[0].w); \
        t0_.u[2] = pk2bf(r[1].x, r[1].y); t0_.u[3] = pk2bf(r[1].z, r[1].w); \
        t1_.u[0] = pk2bf(r[2].x, r[2].y); t1_.u[1] = pk2bf(r[2].z, r[2].w); \
        t1_.u[2] = pk2bf(r[3].x, r[3].y); t1_.u[3] = pk2bf(r[3].z, r[3].w); \
        *(short8*)(lds.tile[buf] + sd0) = t0_.s;                        \
        *(short8*)(lds.tile[buf] + sd1) = t1_.s;                        \
    } while (0)

    // ---- compute-side fragment offsets (identical for both stages) ---------
    int aoff[2];
#pragma unroll
    for (int g = 0; g < 2; ++g) {
        int row = w * 32 + g * 16 + lrow;      // m (s1) / n (s2)
        aoff[g] = row * 32 + ((quad ^ ((row >> 1) & 3)) * 8);
    }

    const unsigned short* wptr[4];
#pragma unroll
    for (int ot = 0; ot < 4; ++ot)
        wptr[ot] = Wslice + (size_t)(ot * 16 + lrow) * 512 + quad * 8;

    float bv[4];
#pragma unroll
    for (int j = 0; j < 4; ++j) bv[j] = bias[ks * 64 + 16 * j + lrow];

    // ---------------- Stage 1: X[b] @ W-slice -------------------------------
    floatx4 acc1[2][4];
    const floatx4 fzero = {0.f, 0.f, 0.f, 0.f};
#pragma unroll
    for (int g = 0; g < 2; ++g)
#pragma unroll
        for (int j = 0; j < 4; ++j) acc1[g][j] = fzero;

    float4 xr[4];
    short8 wfr[2][4];

    LOADG(xr, xsrc, 0);
    WRITET(0, xr);                       // prolog: pays latency once
    LOADG(xr, xsrc, 32);
#pragma unroll
    for (int ot = 0; ot < 4; ++ot) wfr[0][ot] = *(const short8*)(wptr[ot]);
    __syncthreads();                     // buf0 ready

#pragma unroll
    for (int kb = 0; kb < 16; ++kb) {
        const int cur = kb & 1;
        if (kb < 15) {
            WRITET(cur ^ 1, xr);         // xr drained at last barrier: no stall
#pragma unroll
            for (int ot = 0; ot < 4; ++ot)
                wfr[cur ^ 1][ot] = *(const short8*)(wptr[ot] + (kb + 1) * 32);
        }
        if (kb < 14) LOADG(xr, xsrc, (kb + 2) * 32);   // in flight over compute
        short8 af0 = *(const short8*)(lds.tile[cur] + aoff[0]);
        short8 af1 = *(const short8*)(lds.tile[cur] + aoff[1]);
#pragma unroll
        for (int ot = 0; ot < 4; ++ot) {
            acc1[0][ot] = __builtin_amdgcn_mfma_f32_16x16x32_bf16(af0, wfr[cur][ot], acc1[0][ot], 0, 0, 0);
            acc1[1][ot] = __builtin_amdgcn_mfma_f32_16x16x32_bf16(af1, wfr[cur][ot], acc1[1][ot], 0, 0, 0);
        }
        __syncthreads();                 // next buffer ready for everyone
    }

    // ------- transition: issue adj loads, write ht, prime stage-2 pipe ------
    float4 ar[4];
    LOADG(ar, asrc, 0);                  // latency hides under ht epilogue

#pragma unroll
    for (int g = 0; g < 2; ++g) {
#pragma unroll
        for (int j = 0; j < 4; ++j) {
            int d = 16 * j + lrow;               // C/D col = lane&15
            floatx4 c = acc1[g][j];
            unsigned p01 = pk2bf(fmaxf(c.x + bv[j], 0.f), fmaxf(c.y + bv[j], 0.f));
            unsigned p23 = pk2bf(fmaxf(c.z + bv[j], 0.f), fmaxf(c.w + bv[j], 0.f));
            int jm = 4 * w + 2 * g + (quad >> 1);  // 16-B chunk = m>>3
            int phys = jm ^ (d & 7);               // ht swizzle
            unsigned* d32 = (unsigned*)(lds.ht + d * 256 + phys * 8 + (quad & 1) * 4);
            d32[0] = p01; d32[1] = p23;            // rows m..m+3 (8 B)
        }
    }
    WRITET(0, ar);                       // tile[0] free (last read at kb=14)
    LOADG(ar, asrc, 32);
    __syncthreads();                     // ht + adj buf0 ready

    // ------------- Stage 2: adj[b,ks] @ ht -> out ---------------------------
    floatx4 acc2[2][4];
#pragma unroll
    for (int g = 0; g < 2; ++g)
#pragma unroll
        for (int j = 0; j < 4; ++j) acc2[g][j] = fzero;

#pragma unroll
    for (int mt = 0; mt < 8; ++mt) {
        const int cur = mt & 1;
        if (mt < 7) WRITET(cur ^ 1, ar);
        if (mt < 6) LOADG(ar, asrc, (mt + 2) * 32);
        short8 af0 = *(const short8*)(lds.tile[cur] + aoff[0]);
        short8 af1 = *(const short8*)(lds.tile[cur] + aoff[1]);
#pragma unroll
        for (int dt = 0; dt < 4; ++dt) {
            int d = dt * 16 + lrow;
            int jm = 4 * mt + quad;
            short8 hf = *(const short8*)(lds.ht + d * 256 + ((jm ^ (d & 7)) * 8));
            acc2[0][dt] = __builtin_amdgcn_mfma_f32_16x16x32_bf16(af0, hf, acc2[0][dt], 0, 0, 0);
            acc2[1][dt] = __builtin_amdgcn_mfma_f32_16x16x32_bf16(af1, hf, acc2[1][dt], 0, 0, 0);
        }
        if (mt < 7) __syncthreads();
    }

    // epilogue: C/D col = lane&15 (d), row = quad*4+reg (n)
#pragma unroll
    for (int g = 0; g < 2; ++g) {
        const int n_g = w * 32 + g * 16 + quad * 4;
        float* dst = out + ((size_t)b * 256 + n_g) * 512 + ks * 64 + lrow;
#pragma unroll
        for (int dt = 0; dt < 4; ++dt) {
            float* p = dst + dt * 16;
            p[0 * 512] = acc2[g][dt].x;
            p[1 * 512] = acc2[g][dt].y;
            p[2 * 512] = acc2[g][dt].z;
            p[3 * 512] = acc2[g][dt].w;
        }
    }
#undef LOADG
#undef WRITET
}

// ---------------------------------------------------------------------------
extern "C" void kernel_launch(void* const* d_in, const int* in_sizes, int n_in,
                              void* d_out, int out_size, void* d_ws, size_t ws_size,
                              hipStream_t stream) {
    const float* X    = (const float*)d_in[0];  // node_feats
    const float* adj  = (const float*)d_in[1];  // adj
    const float* W    = (const float*)d_in[2];  // weight
    const float* bias = (const float*)d_in[3];  // bias
    float* out = (float*)d_out;

    // workspace: Wt bf16 [512*512] only
    unsigned short* Wt = (unsigned short*)d_ws;

    wt_kernel<<<64, 256, 0, stream>>>(W, Wt);
    fused_kernel<<<512, 512, 0, stream>>>(X, Wt, bias, adj, out);
}